// Round 13
// baseline (237.066 us; speedup 1.0000x reference)
//
#include <hip/hip_runtime.h>
#include <math.h>

#define BB 2
#define NPTS 1024
#define KK 64
#define NSZ 32
#define CC 1331      // 11^3
#define FF 32
#define RAD2 1.0f
#define NCOL 121     // 11*11 (ix,iy) columns
#define NRNG 8       // point ranges per batch (128 pts each)
#define NBLK 256     // persistent blocks (1 per CU)
#define NTHR 512

// device-scope grid barrier: counter per barrier id, reset by memset each launch.
__device__ __forceinline__ void gbar(unsigned* bar, int id) {
    __syncthreads();
    if (threadIdx.x == 0) {
        __threadfence();
        __hip_atomic_fetch_add(&bar[id], 1u, __ATOMIC_ACQ_REL, __HIP_MEMORY_SCOPE_AGENT);
        while (__hip_atomic_load(&bar[id], __ATOMIC_ACQUIRE, __HIP_MEMORY_SCOPE_AGENT) < NBLK) {
            __builtin_amdgcn_s_sleep(8);
        }
        __threadfence();
    }
    __syncthreads();
}

__global__ __launch_bounds__(NTHR, 2)
void k_all(const float* __restrict__ src_pts, const float* __restrict__ tgt_pts,
           const float* __restrict__ R,
           const float* __restrict__ W1, const float* __restrict__ b1,
           const float* __restrict__ W2, const float* __restrict__ b2,
           const float* __restrict__ Ww1, const float* __restrict__ bw1,
           const float* __restrict__ Ww2, const float* __restrict__ bw2,
           const float* __restrict__ Wd1, const float* __restrict__ bd1,
           const float* __restrict__ Wd2, const float* __restrict__ bd2,
           float* src_feat, float* tgt_A, float* tgt_m2, float* score,
           int* key_idx, float* kxyz, float* kxyz_t, float* src_emb,
           float* sim, float2* part, unsigned* bar,
           float* out_kxyz, float* out_vcp)
{
    const int bid = blockIdx.x;
    const int t = threadIdx.x;
    __shared__ float4 P[128];
    __shared__ float2 pbuf[4][NCOL][11];
    __shared__ float sc[NPTS];
    __shared__ float kxs[KK][3];
    __shared__ float embs[NSZ][FF];
    __shared__ float red[NTHR];
    __shared__ float4 red4[NTHR];

    // ================= P1: feature MLPs + score + tgt m2 + A-precompute ==========
    {
        int gid = bid * NTHR + t;                  // 0..131071; active < 4096
        if (gid < 2 * BB * NPTS) {
            int isTgt = gid >= BB * NPTS;
            int pn = gid & (BB * NPTS - 1);
            int b = pn >> 10, n = pn & 1023;
            const float* pts = isTgt ? tgt_pts : src_pts;
            float p[6];
#pragma unroll
            for (int i = 0; i < 6; i++) p[i] = pts[(b * 6 + i) * NPTS + n];
            float h[FF];
#pragma unroll
            for (int j = 0; j < FF; j++) {
                float a = b1[j];
#pragma unroll
                for (int i = 0; i < 6; i++) a = fmaf(p[i], W1[i * FF + j], a);
                h[j] = fmaxf(a, 0.0f);
            }
            float ft[FF];
#pragma unroll
            for (int j = 0; j < FF; j++) {
                float a = b2[j];
#pragma unroll
                for (int i = 0; i < FF; i++) a = fmaf(h[i], W2[i * FF + j], a);
                ft[j] = fmaxf(a, 0.0f);
            }
            if (isTgt) {
                float x = p[0], y = p[1], z = p[2];
                float4 v; v.x = x; v.y = y; v.z = z; v.w = x * x + y * y + z * z;
                ((float4*)tgt_m2)[b * NPTS + n] = v;
                float av[FF];
#pragma unroll
                for (int j = 0; j < FF; j++) av[j] = bd1[j];
#pragma unroll
                for (int i = 0; i < FF; i++) {
                    float fi = ft[i];
#pragma unroll
                    for (int j = 0; j < FF; j++)
                        av[j] = fmaf(fi, Wd1[(3 + i) * FF + j], av[j]);
                }
#pragma unroll
                for (int j = 0; j < FF; j++) tgt_A[(b * NPTS + n) * FF + j] = av[j];
            } else {
#pragma unroll
                for (int j = 0; j < FF; j++) src_feat[(b * NPTS + n) * FF + j] = ft[j];
                float acc = bw2[0];
#pragma unroll
                for (int j = 0; j < 16; j++) {
                    float a = bw1[j];
#pragma unroll
                    for (int i = 0; i < FF; i++) a = fmaf(ft[i], Ww1[i * 16 + j], a);
                    acc = fmaf(fmaxf(a, 0.0f), Ww2[j], acc);
                }
                score[b * NPTS + n] = acc;
            }
        }
    }
    gbar(bar, 0);

    // ================= P2: rank-based top-K (exact lax.top_k order) ===============
    if (bid < BB * 16) {
        int b = bid >> 4;
        int pbase = (bid & 15) << 6;               // 64 points per vblock
        for (int i = t; i < NPTS; i += NTHR) sc[i] = score[b * NPTS + i];
        __syncthreads();
        if (t < 256) {
            int sub = t & 3;
            int lp = t >> 2;
            int n = pbase + lp;
            float s = sc[n];
            int rank = 0;
#pragma unroll 8
            for (int jj = 0; jj < 256; jj++) {
                int j = (jj << 2) | sub;
                float sj = sc[j];
                bool before = (sj > s) || (sj == s && j < n);
                rank += before ? 1 : 0;
            }
            rank += __shfl_xor(rank, 1, 64);
            rank += __shfl_xor(rank, 2, 64);
            if (sub == 0 && rank < KK) {
                key_idx[b * KK + rank] = n;
                float x = src_pts[(b * 6 + 0) * NPTS + n];
                float y = src_pts[(b * 6 + 1) * NPTS + n];
                float z = src_pts[(b * 6 + 2) * NPTS + n];
                int o = (b * KK + rank) * 3;
                kxyz[o] = x; kxyz[o + 1] = y; kxyz[o + 2] = z;
                out_kxyz[o] = x; out_kxyz[o + 1] = y; out_kxyz[o + 2] = z;
#pragma unroll
                for (int i = 0; i < 3; i++)
                    kxyz_t[o + i] = R[i * 3 + 0] * x + R[i * 3 + 1] * y + R[i * 3 + 2] * z;
            }
        }
    }
    gbar(bar, 1);

    // ================= P3a: separable NN scan (all 256 blocks) ====================
    // block -> (bk = bid>>1, half = bid&1); 4 passes over ranges rr = half*4+pass.
    // 4 units x 128 threads; unit u scans 32 of the 128 staged points.
    {
        int bk = bid >> 1, half = bid & 1;
        int b = bk >> 6;
        int u = t >> 7, lt = t & 127;
        float kx = kxyz_t[bk * 3 + 0], ky = kxyz_t[bk * 3 + 1], kz = kxyz_t[bk * 3 + 2];
        float kx2 = -2.0f * kx, ky2 = -2.0f * ky, kz2 = -2.0f * kz;
        bool active = lt < NCOL;
        int pc = active ? lt : 0;
        int ixv = pc / 11, iyv = pc - ixv * 11;
        float gx2 = -2.0f * (-2.0f + ixv * 0.4f);
        float gy2 = -2.0f * (-2.0f + iyv * 0.4f);
        float gz2[11];
#pragma unroll
        for (int iz = 0; iz < 11; iz++) gz2[iz] = -2.0f * (-2.0f + iz * 0.4f);
        for (int pass = 0; pass < 4; pass++) {
            int rr = half * 4 + pass;
            if (t < 128) P[t] = ((const float4*)tgt_m2)[(b << 10) + (rr << 7) + t];
            __syncthreads();
            if (active) {
                float best[11]; int bn[11];
#pragma unroll
                for (int iz = 0; iz < 11; iz++) { best[iz] = 3.0e38f; bn[iz] = 0; }
                const int pb = u << 5;             // unit scans 32 points
#pragma unroll 8
                for (int i = 0; i < 32; i++) {
                    float4 v = P[pb + i];
                    float a = fmaf(kx2, v.x, fmaf(ky2, v.y, fmaf(kz2, v.z, v.w)));
                    float e = fmaf(gx2, v.x, fmaf(gy2, v.y, a));
#pragma unroll
                    for (int iz = 0; iz < 11; iz++) {
                        float d = fmaf(gz2[iz], v.z, e);
                        bool l = d < best[iz];     // strict <: first-min in scan order
                        best[iz] = l ? d : best[iz];
                        bn[iz] = l ? i : bn[iz];
                    }
                }
#pragma unroll
                for (int iz = 0; iz < 11; iz++)
                    pbuf[u][lt][iz] = make_float2(best[iz],
                        __int_as_float(bn[iz] + (u << 5)));
            }
            __syncthreads();
            // merge 4 units (ascending u = ascending points) + write partial
            for (int ci = t; ci < CC; ci += NTHR) {
                int p = ci / 11, iz = ci - p * 11;
                float2 m = pbuf[0][p][iz];
#pragma unroll
                for (int u2 = 1; u2 < 4; u2++) {
                    float2 o = pbuf[u2][p][iz];
                    if (o.x < m.x) m = o;
                }
                part[((bk << 3) + rr) * CC + ci] = make_float2(m.x,
                    __int_as_float(__float_as_int(m.y) + (rr << 7)));
            }
            __syncthreads();
        }
    }
    // ================= P3b: radius grouping + src dfe + maxpool (bid<128) =========
    if (bid < BB * KK) {
        int b = bid >> 6, kk = bid & 63;
        if (t < KK) {
            kxs[t][0] = kxyz[(b * KK + t) * 3 + 0];
            kxs[t][1] = kxyz[(b * KK + t) * 3 + 1];
            kxs[t][2] = kxyz[(b * KK + t) * 3 + 2];
        }
        __syncthreads();
        if (t < KK) {
            float cx = kxs[kk][0], cy = kxs[kk][1], cz = kxs[kk][2];
            float dx = kxs[t][0] - cx, dy = kxs[t][1] - cy, dz = kxs[t][2] - cz;
            float sq = dx * dx + dy * dy + dz * dz;
            unsigned long long mask = __ballot(sq <= RAD2);   // wave 0 only
            if (t < NSZ) {
                int cnt = __popcll(mask);
                int want = (t < cnt) ? t : 0;
                unsigned long long mm = mask;
                for (int q = 0; q < want; q++) mm &= (mm - 1);
                int g = __ffsll(mm) - 1;
                float xr = kxs[g][0] - cx, yr = kxs[g][1] - cy, zr = kxs[g][2] - cz;
                int orig = key_idx[b * KK + g];
                const float* fz = &src_feat[(b * NPTS + orig) * FF];
                float fr[FF];
#pragma unroll
                for (int i = 0; i < FF; i++) fr[i] = fz[i];
                float h[FF];
#pragma unroll
                for (int j = 0; j < FF; j++) {
                    float a = bd1[j];
                    a = fmaf(xr, Wd1[0 * FF + j], a);
                    a = fmaf(yr, Wd1[1 * FF + j], a);
                    a = fmaf(zr, Wd1[2 * FF + j], a);
#pragma unroll
                    for (int i = 0; i < FF; i++) a = fmaf(fr[i], Wd1[(3 + i) * FF + j], a);
                    h[j] = fmaxf(a, 0.0f);
                }
#pragma unroll
                for (int j = 0; j < FF; j++) {
                    float a = bd2[j];
#pragma unroll
                    for (int i = 0; i < FF; i++) a = fmaf(h[i], Wd2[i * FF + j], a);
                    embs[t][j] = fmaxf(a, 0.0f);
                }
            }
        }
        __syncthreads();
        if (t < FF) {
            float m = embs[0][t];
#pragma unroll
            for (int s2 = 1; s2 < NSZ; s2++) m = fmaxf(m, embs[s2][t]);
            src_emb[(b * KK + kk) * FF + t] = m;
        }
    }
    gbar(bar, 2);

    // ================= P4: merge partials -> gather A -> slim dfe -> sim ==========
#pragma unroll
    for (int pass = 0; pass < 2; pass++) {
        int ci = pass * (NBLK * NTHR) + bid * NTHR + t;
        if (ci < BB * KK * CC) {
            int bk = ci / CC;
            int c = ci - bk * CC;
            int b = bk >> 6;
            float2 rb = part[(bk << 3) * CC + c];
#pragma unroll
            for (int r = 1; r < NRNG; r++) {
                float2 o = part[((bk << 3) + r) * CC + c];
                if (o.x < rb.x) rb = o;            // ascending r, strict <
            }
            int nb = __float_as_int(rb.y);
            float4 nv = ((const float4*)tgt_m2)[(b << 10) + nb];
            const float4* az = (const float4*)&tgt_A[((b << 10) + nb) * FF];
            float h[FF];
#pragma unroll
            for (int i = 0; i < FF / 4; i++) {
                float4 v = az[i];
                h[i * 4 + 0] = v.x; h[i * 4 + 1] = v.y;
                h[i * 4 + 2] = v.z; h[i * 4 + 3] = v.w;
            }
            int ixv = c / 121, rem = c - ixv * 121, iyv = rem / 11, izv = rem - iyv * 11;
            float cx = kxyz_t[bk * 3 + 0] + (-2.0f + ixv * 0.4f);
            float cy = kxyz_t[bk * 3 + 1] + (-2.0f + iyv * 0.4f);
            float cz = kxyz_t[bk * 3 + 2] + (-2.0f + izv * 0.4f);
            float x0 = cx - nv.x, x1 = cy - nv.y, x2 = cz - nv.z;
#pragma unroll
            for (int j = 0; j < FF; j++) {
                float a = h[j];
                a = fmaf(x0, Wd1[0 * FF + j], a);
                a = fmaf(x1, Wd1[1 * FF + j], a);
                a = fmaf(x2, Wd1[2 * FF + j], a);
                h[j] = fmaxf(a, 0.0f);
            }
            float sv = 0.0f;
#pragma unroll
            for (int j = 0; j < FF; j++) {
                float a = bd2[j];
#pragma unroll
                for (int i = 0; i < FF; i++) a = fmaf(h[i], Wd2[i * FF + j], a);
                sv = fmaf(fmaxf(a, 0.0f), src_emb[bk * FF + j], sv);
            }
            sim[bk * CC + c] = sv;
        }
    }
    gbar(bar, 3);

    // ================= P5: softmax + weighted candidate sum (bid<128) =============
    if (bid < BB * KK) {
        int bk = bid;
        float kx = kxyz_t[bk * 3 + 0], ky = kxyz_t[bk * 3 + 1], kz = kxyz_t[bk * 3 + 2];
        float lm = -3.0e38f;
        for (int c = t; c < CC; c += NTHR) lm = fmaxf(lm, sim[bk * CC + c]);
        red[t] = lm;
        __syncthreads();
        for (int s2 = NTHR / 2; s2 > 0; s2 >>= 1) {
            if (t < s2) red[t] = fmaxf(red[t], red[t + s2]);
            __syncthreads();
        }
        float m = red[0];
        float se = 0.f, sx = 0.f, sy = 0.f, sz = 0.f;
        for (int c = t; c < CC; c += NTHR) {
            float e = expf(sim[bk * CC + c] - m);
            int ix = c / 121, rem = c - ix * 121, iy = rem / 11, iz = rem - iy * 11;
            float cxx = kx + (-2.0f + ix * 0.4f);
            float cyy = ky + (-2.0f + iy * 0.4f);
            float czz = kz + (-2.0f + iz * 0.4f);
            se += e;
            sx = fmaf(e, cxx, sx);
            sy = fmaf(e, cyy, sy);
            sz = fmaf(e, czz, sz);
        }
        red4[t] = make_float4(se, sx, sy, sz);
        __syncthreads();
        for (int s2 = NTHR / 2; s2 > 0; s2 >>= 1) {
            if (t < s2) {
                float4 a = red4[t], bq = red4[t + s2];
                red4[t] = make_float4(a.x + bq.x, a.y + bq.y, a.z + bq.z, a.w + bq.w);
            }
            __syncthreads();
        }
        if (t == 0) {
            float4 r = red4[0];
            out_vcp[bk * 3 + 0] = r.y / r.x;
            out_vcp[bk * 3 + 1] = r.z / r.x;
            out_vcp[bk * 3 + 2] = r.w / r.x;
        }
    }
}

extern "C" void kernel_launch(void* const* d_in, const int* in_sizes, int n_in,
                              void* d_out, int out_size, void* d_ws, size_t ws_size,
                              hipStream_t stream)
{
    (void)in_sizes; (void)n_in; (void)out_size; (void)ws_size;
    const float* src_pts = (const float*)d_in[0];
    const float* tgt_pts = (const float*)d_in[1];
    const float* R_init  = (const float*)d_in[2];
    const float* W1  = (const float*)d_in[4];
    const float* b1  = (const float*)d_in[5];
    const float* W2  = (const float*)d_in[6];
    const float* b2  = (const float*)d_in[7];
    const float* Ww1 = (const float*)d_in[8];
    const float* bw1 = (const float*)d_in[9];
    const float* Ww2 = (const float*)d_in[10];
    const float* bw2 = (const float*)d_in[11];
    const float* Wd1 = (const float*)d_in[12];
    const float* bd1 = (const float*)d_in[13];
    const float* Wd2 = (const float*)d_in[14];
    const float* bd2 = (const float*)d_in[15];

    float* ws = (float*)d_ws;
    float* src_feat = ws;                              // 65536 floats
    float* tgt_A    = src_feat + BB * NPTS * FF;       // 65536
    float* tgt_m2   = tgt_A + BB * NPTS * FF;          // 8192
    float* score    = tgt_m2 + BB * NPTS * 4;          // 2048
    int*   key_idx  = (int*)(score + BB * NPTS);       // 128
    float* kxyz     = (float*)(key_idx + BB * KK);     // 384
    float* kxyz_t   = kxyz + BB * KK * 3;              // 384
    float* src_emb  = kxyz_t + BB * KK * 3;            // 4096
    float* sim      = src_emb + BB * KK * FF;          // 170368
    float2* part    = (float2*)(sim + BB * KK * CC);   // 128*8*1331 float2
    unsigned* bar   = (unsigned*)(part + BB * KK * NRNG * CC);  // 64 B counters

    float* out_kxyz = (float*)d_out;
    float* out_vcp  = out_kxyz + BB * KK * 3;

    hipMemsetAsync(bar, 0, 64, stream);
    k_all<<<NBLK, NTHR, 0, stream>>>(
        src_pts, tgt_pts, R_init,
        W1, b1, W2, b2, Ww1, bw1, Ww2, bw2, Wd1, bd1, Wd2, bd2,
        src_feat, tgt_A, tgt_m2, score, key_idx, kxyz, kxyz_t, src_emb,
        sim, part, bar, out_kxyz, out_vcp);
}

// Round 14
// 167.377 us; speedup vs baseline: 1.4164x; 1.4164x over previous
//
#include <hip/hip_runtime.h>
#include <math.h>

#define BB 2
#define NPTS 1024
#define KK 64
#define NSZ 32
#define CC 1331      // 11^3
#define FF 32
#define RAD2 1.0f
#define NCOL 121     // 11*11 (ix,iy) columns
#define NRNG 8       // point ranges per batch (128 pts each)

// ---------------- K1: feature MLPs + score + tgt (x,y,z,|t|^2) + A-precompute ------
__global__ __launch_bounds__(64)
void k_features(const float* __restrict__ src_pts, const float* __restrict__ tgt_pts,
                const float* __restrict__ W1, const float* __restrict__ b1,
                const float* __restrict__ W2, const float* __restrict__ b2,
                const float* __restrict__ Ww1, const float* __restrict__ bw1,
                const float* __restrict__ Ww2, const float* __restrict__ bw2,
                const float* __restrict__ Wd1, const float* __restrict__ bd1,
                float* __restrict__ src_feat, float* __restrict__ tgt_A,
                float* __restrict__ tgt_m2, float* __restrict__ score)
{
    int gid = blockIdx.x * blockDim.x + threadIdx.x;   // 0..4095
    int isTgt = gid >= BB * NPTS;
    int pn = gid & (BB * NPTS - 1);
    int b = pn >> 10, n = pn & 1023;
    const float* pts = isTgt ? tgt_pts : src_pts;
    float p[6];
#pragma unroll
    for (int i = 0; i < 6; i++) p[i] = pts[(b * 6 + i) * NPTS + n];
    float h[FF];
#pragma unroll
    for (int j = 0; j < FF; j++) {
        float a = b1[j];
#pragma unroll
        for (int i = 0; i < 6; i++) a = fmaf(p[i], W1[i * FF + j], a);
        h[j] = fmaxf(a, 0.0f);
    }
    float ft[FF];
#pragma unroll
    for (int j = 0; j < FF; j++) {
        float a = b2[j];
#pragma unroll
        for (int i = 0; i < FF; i++) a = fmaf(h[i], W2[i * FF + j], a);
        ft[j] = fmaxf(a, 0.0f);
    }
    if (isTgt) {
        float x = p[0], y = p[1], z = p[2];
        float4 v; v.x = x; v.y = y; v.z = z; v.w = x * x + y * y + z * z;
        ((float4*)tgt_m2)[b * NPTS + n] = v;
        float av[FF];
#pragma unroll
        for (int j = 0; j < FF; j++) av[j] = bd1[j];
#pragma unroll
        for (int i = 0; i < FF; i++) {
            float fi = ft[i];
#pragma unroll
            for (int j = 0; j < FF; j++)
                av[j] = fmaf(fi, Wd1[(3 + i) * FF + j], av[j]);
        }
#pragma unroll
        for (int j = 0; j < FF; j++) tgt_A[(b * NPTS + n) * FF + j] = av[j];
    } else {
#pragma unroll
        for (int j = 0; j < FF; j++) src_feat[(b * NPTS + n) * FF + j] = ft[j];
        float acc = bw2[0];
#pragma unroll
        for (int j = 0; j < 16; j++) {
            float a = bw1[j];
#pragma unroll
            for (int i = 0; i < FF; i++) a = fmaf(ft[i], Ww1[i * 16 + j], a);
            acc = fmaf(fmaxf(a, 0.0f), Ww2[j], acc);
        }
        score[b * NPTS + n] = acc;
    }
}

// ---------------- K2: rank-based top-K + nnkey init ----------------
__global__ __launch_bounds__(256)
void k_rank(const float* __restrict__ score, const float* __restrict__ src_pts,
            const float* __restrict__ R,
            int* __restrict__ key_idx, float* __restrict__ kxyz,
            float* __restrict__ kxyz_t, float* __restrict__ out_kxyz,
            unsigned long long* __restrict__ nnkey)
{
    int blk = blockIdx.x;            // 0..BB*16-1
    int b = blk >> 4;
    int pbase = (blk & 15) << 6;     // 64 points per block
    int t = threadIdx.x;
    // init nnkey for atomicMin (runs before k_scan by stream order)
    int gid = blk * 256 + t;         // 0..8191
    for (int i = gid; i < BB * KK * CC; i += BB * 16 * 256)
        nnkey[i] = 0xFFFFFFFFFFFFFFFFull;
    int sub = t & 3;                 // j-partition 0..3
    int lp = t >> 2;                 // local point 0..63
    int n = pbase + lp;
    __shared__ float sc[NPTS];
    for (int i = t; i < NPTS; i += 256) sc[i] = score[b * NPTS + i];
    __syncthreads();
    float s = sc[n];
    int rank = 0;
#pragma unroll 8
    for (int jj = 0; jj < 256; jj++) {
        int j = (jj << 2) | sub;
        float sj = sc[j];
        bool before = (sj > s) || (sj == s && j < n);
        rank += before ? 1 : 0;
    }
    rank += __shfl_xor(rank, 1, 64);
    rank += __shfl_xor(rank, 2, 64);
    if (sub == 0 && rank < KK) {
        key_idx[b * KK + rank] = n;
        float x = src_pts[(b * 6 + 0) * NPTS + n];
        float y = src_pts[(b * 6 + 1) * NPTS + n];
        float z = src_pts[(b * 6 + 2) * NPTS + n];
        int o = (b * KK + rank) * 3;
        kxyz[o] = x; kxyz[o + 1] = y; kxyz[o + 2] = z;
        out_kxyz[o] = x; out_kxyz[o + 1] = y; out_kxyz[o + 2] = z;
#pragma unroll
        for (int i = 0; i < 3; i++)
            kxyz_t[o + i] = R[i * 3 + 0] * x + R[i * 3 + 1] * y + R[i * 3 + 2] * z;
    }
}

// ---------------- K3: radius grouping + src dfe + maxpool ----------------
__global__ __launch_bounds__(64)
void k_group_emb(const float* __restrict__ kxyz, const int* __restrict__ key_idx,
                 const float* __restrict__ src_feat,
                 const float* __restrict__ Wd1, const float* __restrict__ bd1,
                 const float* __restrict__ Wd2, const float* __restrict__ bd2,
                 float* __restrict__ src_emb)
{
    int b = blockIdx.x / KK, kk = blockIdx.x % KK;
    int t = threadIdx.x;
    __shared__ float kx[KK][3];
    __shared__ float emb[NSZ][FF];
    kx[t][0] = kxyz[(b * KK + t) * 3 + 0];
    kx[t][1] = kxyz[(b * KK + t) * 3 + 1];
    kx[t][2] = kxyz[(b * KK + t) * 3 + 2];
    __syncthreads();
    float cx = kx[kk][0], cy = kx[kk][1], cz = kx[kk][2];
    float dx = kx[t][0] - cx, dy = kx[t][1] - cy, dz = kx[t][2] - cz;
    float sq = dx * dx + dy * dy + dz * dz;
    unsigned long long mask = __ballot(sq <= RAD2);
    if (t < NSZ) {
        int cnt = __popcll(mask);
        int want = (t < cnt) ? t : 0;
        unsigned long long mm = mask;
        for (int q = 0; q < want; q++) mm &= (mm - 1);
        int g = __ffsll(mm) - 1;
        float xr = kx[g][0] - cx, yr = kx[g][1] - cy, zr = kx[g][2] - cz;
        int orig = key_idx[b * KK + g];
        const float* fz = &src_feat[(b * NPTS + orig) * FF];
        float fr[FF];
#pragma unroll
        for (int i = 0; i < FF; i++) fr[i] = fz[i];
        float h[FF];
#pragma unroll
        for (int j = 0; j < FF; j++) {
            float a = bd1[j];
            a = fmaf(xr, Wd1[0 * FF + j], a);
            a = fmaf(yr, Wd1[1 * FF + j], a);
            a = fmaf(zr, Wd1[2 * FF + j], a);
#pragma unroll
            for (int i = 0; i < FF; i++) a = fmaf(fr[i], Wd1[(3 + i) * FF + j], a);
            h[j] = fmaxf(a, 0.0f);
        }
#pragma unroll
        for (int j = 0; j < FF; j++) {
            float a = bd2[j];
#pragma unroll
            for (int i = 0; i < FF; i++) a = fmaf(h[i], Wd2[i * FF + j], a);
            emb[t][j] = fmaxf(a, 0.0f);
        }
    }
    __syncthreads();
    if (t < FF) {
        float m = emb[0][t];
#pragma unroll
        for (int s2 = 1; s2 < NSZ; s2++) m = fmaxf(m, emb[s2][t]);
        src_emb[(b * KK + kk) * FF + t] = m;
    }
}

// ---------------- K4: separable NN scan -> 64-bit atomicMin ----------------
// grid = 128 bk x 8 ranges (128 pts). Block = 256 thr = 2 units x 128 (121 active);
// unit u scans 64 points, then fires 11 atomicMin with key = sortable(d)<<32 | n.
// Key order == (d, n) lexicographic: ties -> lowest n = argmin first-occurrence.
__global__ __launch_bounds__(256)
void k_scan(const float* __restrict__ kxyz_t, const float* __restrict__ tgt_m2,
            unsigned long long* __restrict__ nnkey)
{
    int bid = blockIdx.x;
    int bk = bid >> 3, r = bid & 7;
    int b = bk >> 6;
    int t = threadIdx.x;
    int u = t >> 7, lt = t & 127;
    __shared__ float4 P[128];            // 2 KB (only LDS now)
    if (t < 128) P[t] = ((const float4*)tgt_m2)[(b << 10) + (r << 7) + t];
    float kx = kxyz_t[bk * 3 + 0], ky = kxyz_t[bk * 3 + 1], kz = kxyz_t[bk * 3 + 2];
    float kx2 = -2.0f * kx, ky2 = -2.0f * ky, kz2 = -2.0f * kz;
    bool active = lt < NCOL;
    int pc = active ? lt : 0;
    int ixv = pc / 11, iyv = pc - ixv * 11;
    float gx2 = -2.0f * (-2.0f + ixv * 0.4f);
    float gy2 = -2.0f * (-2.0f + iyv * 0.4f);
    float gz2[11];
#pragma unroll
    for (int iz = 0; iz < 11; iz++) gz2[iz] = -2.0f * (-2.0f + iz * 0.4f);
    float best[11]; int bn[11];
#pragma unroll
    for (int iz = 0; iz < 11; iz++) { best[iz] = 3.0e38f; bn[iz] = 0; }
    __syncthreads();
    if (active) {
        const int pb = u << 6;           // unit scans 64 points
#pragma unroll 8
        for (int i = 0; i < 64; i++) {
            float4 v = P[pb + i];        // wave-uniform addr -> LDS broadcast
            float a = fmaf(kx2, v.x, fmaf(ky2, v.y, fmaf(kz2, v.z, v.w)));
            float e = fmaf(gx2, v.x, fmaf(gy2, v.y, a));
#pragma unroll
            for (int iz = 0; iz < 11; iz++) {
                float d = fmaf(gz2[iz], v.z, e);
                bool l = d < best[iz];   // strict <: first-min in scan order
                best[iz] = l ? d : best[iz];
                bn[iz] = l ? i : bn[iz];
            }
        }
        unsigned long long* base = &nnkey[(unsigned)bk * CC + pc * 11];
#pragma unroll
        for (int iz = 0; iz < 11; iz++) {
            unsigned bb2 = __float_as_uint(best[iz]);
            unsigned m = ((unsigned)(((int)bb2) >> 31)) | 0x80000000u;
            unsigned nglob = (unsigned)((r << 7) + (u << 6) + bn[iz]);
            unsigned long long key = ((unsigned long long)(bb2 ^ m) << 32) | nglob;
            atomicMin(&base[iz], key);
        }
    }
}

// ---------------- K5: read nnkey -> gather A -> slim dfe -> sim ----------------
// 768 blocks x 256 thr, thread-per-candidate, all-static indexing.
__global__ __launch_bounds__(256)
void k_mlp(const unsigned long long* __restrict__ nnkey, const float* __restrict__ kxyz_t,
           const float* __restrict__ tgt_m2, const float* __restrict__ tgt_A,
           const float* __restrict__ src_emb,
           const float* __restrict__ Wd1,
           const float* __restrict__ Wd2, const float* __restrict__ bd2,
           float* __restrict__ sim)
{
    const int NCH = 6;                   // ceil(1331/256)
    int bid = blockIdx.x;
    int chunk = bid % NCH;
    int bk = bid / NCH;
    int b = bk >> 6;
    int t = threadIdx.x;
    int c = chunk * 256 + t;
    int cc = min(c, CC - 1);
    int nb = (int)(unsigned)(nnkey[(unsigned)bk * CC + cc] & 0xFFFFFFFFull);
    float4 nv = ((const float4*)tgt_m2)[(b << 10) + nb];
    const float4* az = (const float4*)&tgt_A[((b << 10) + nb) * FF];
    float h[FF];
#pragma unroll
    for (int i = 0; i < FF / 4; i++) {
        float4 v = az[i];
        h[i * 4 + 0] = v.x; h[i * 4 + 1] = v.y; h[i * 4 + 2] = v.z; h[i * 4 + 3] = v.w;
    }
    int ixv = cc / 121, rem = cc - ixv * 121, iyv = rem / 11, izv = rem - iyv * 11;
    float cx = kxyz_t[bk * 3 + 0] + (-2.0f + ixv * 0.4f);
    float cy = kxyz_t[bk * 3 + 1] + (-2.0f + iyv * 0.4f);
    float cz = kxyz_t[bk * 3 + 2] + (-2.0f + izv * 0.4f);
    float x0 = cx - nv.x, x1 = cy - nv.y, x2 = cz - nv.z;
#pragma unroll
    for (int j = 0; j < FF; j++) {
        float a = h[j];
        a = fmaf(x0, Wd1[0 * FF + j], a);
        a = fmaf(x1, Wd1[1 * FF + j], a);
        a = fmaf(x2, Wd1[2 * FF + j], a);
        h[j] = fmaxf(a, 0.0f);
    }
    float sv = 0.0f;
#pragma unroll
    for (int j = 0; j < FF; j++) {
        float a = bd2[j];
#pragma unroll
        for (int i = 0; i < FF; i++) a = fmaf(h[i], Wd2[i * FF + j], a);
        sv = fmaf(fmaxf(a, 0.0f), src_emb[bk * FF + j], sv);
    }
    if (c < CC) sim[bk * CC + c] = sv;
}

// ---------------- K6: softmax over candidates + weighted sum ----------------
__global__ __launch_bounds__(256)
void k_softmax(const float* __restrict__ sim, const float* __restrict__ kxyz_t,
               float* __restrict__ out_vcp)
{
    int bk = blockIdx.x;
    int t = threadIdx.x;
    __shared__ float red[256];
    __shared__ float4 red4[256];
    float kx = kxyz_t[bk * 3 + 0], ky = kxyz_t[bk * 3 + 1], kz = kxyz_t[bk * 3 + 2];
    float lm = -3.0e38f;
    for (int c = t; c < CC; c += 256) lm = fmaxf(lm, sim[bk * CC + c]);
    red[t] = lm;
    __syncthreads();
    for (int s2 = 128; s2 > 0; s2 >>= 1) {
        if (t < s2) red[t] = fmaxf(red[t], red[t + s2]);
        __syncthreads();
    }
    float m = red[0];
    float se = 0.f, sx = 0.f, sy = 0.f, sz = 0.f;
    for (int c = t; c < CC; c += 256) {
        float e = expf(sim[bk * CC + c] - m);
        int ix = c / 121, rem = c - ix * 121, iy = rem / 11, iz = rem - iy * 11;
        float cxx = kx + (-2.0f + ix * 0.4f);
        float cyy = ky + (-2.0f + iy * 0.4f);
        float czz = kz + (-2.0f + iz * 0.4f);
        se += e;
        sx = fmaf(e, cxx, sx);
        sy = fmaf(e, cyy, sy);
        sz = fmaf(e, czz, sz);
    }
    red4[t] = make_float4(se, sx, sy, sz);
    __syncthreads();
    for (int s2 = 128; s2 > 0; s2 >>= 1) {
        if (t < s2) {
            float4 a = red4[t], bq = red4[t + s2];
            red4[t] = make_float4(a.x + bq.x, a.y + bq.y, a.z + bq.z, a.w + bq.w);
        }
        __syncthreads();
    }
    if (t == 0) {
        float4 r = red4[0];
        out_vcp[bk * 3 + 0] = r.y / r.x;
        out_vcp[bk * 3 + 1] = r.z / r.x;
        out_vcp[bk * 3 + 2] = r.w / r.x;
    }
}

extern "C" void kernel_launch(void* const* d_in, const int* in_sizes, int n_in,
                              void* d_out, int out_size, void* d_ws, size_t ws_size,
                              hipStream_t stream)
{
    (void)in_sizes; (void)n_in; (void)out_size; (void)ws_size;
    const float* src_pts = (const float*)d_in[0];
    const float* tgt_pts = (const float*)d_in[1];
    const float* R_init  = (const float*)d_in[2];
    const float* W1  = (const float*)d_in[4];
    const float* b1  = (const float*)d_in[5];
    const float* W2  = (const float*)d_in[6];
    const float* b2  = (const float*)d_in[7];
    const float* Ww1 = (const float*)d_in[8];
    const float* bw1 = (const float*)d_in[9];
    const float* Ww2 = (const float*)d_in[10];
    const float* bw2 = (const float*)d_in[11];
    const float* Wd1 = (const float*)d_in[12];
    const float* bd1 = (const float*)d_in[13];
    const float* Wd2 = (const float*)d_in[14];
    const float* bd2 = (const float*)d_in[15];

    float* ws = (float*)d_ws;
    float* src_feat = ws;                              // 65536
    float* tgt_A    = src_feat + BB * NPTS * FF;       // 65536
    float* tgt_m2   = tgt_A + BB * NPTS * FF;          // 8192
    float* score    = tgt_m2 + BB * NPTS * 4;          // 2048
    int*   key_idx  = (int*)(score + BB * NPTS);       // 128
    float* kxyz     = (float*)(key_idx + BB * KK);     // 384
    float* kxyz_t   = kxyz + BB * KK * 3;              // 384
    float* src_emb  = kxyz_t + BB * KK * 3;            // 4096
    float* sim      = src_emb + BB * KK * FF;          // 170368
    unsigned long long* nnkey = (unsigned long long*)(sim + BB * KK * CC); // 1.36 MB

    float* out_kxyz = (float*)d_out;
    float* out_vcp  = out_kxyz + BB * KK * 3;

    k_features<<<64, 64, 0, stream>>>(
        src_pts, tgt_pts, W1, b1, W2, b2, Ww1, bw1, Ww2, bw2, Wd1, bd1,
        src_feat, tgt_A, tgt_m2, score);
    k_rank<<<BB * 16, 256, 0, stream>>>(score, src_pts, R_init,
                                        key_idx, kxyz, kxyz_t, out_kxyz, nnkey);
    k_group_emb<<<BB * KK, 64, 0, stream>>>(kxyz, key_idx, src_feat,
                                            Wd1, bd1, Wd2, bd2, src_emb);
    k_scan<<<BB * KK * NRNG, 256, 0, stream>>>(kxyz_t, tgt_m2, nnkey);
    k_mlp<<<BB * KK * 6, 256, 0, stream>>>(nnkey, kxyz_t, tgt_m2, tgt_A, src_emb,
                                           Wd1, Wd2, bd2, sim);
    k_softmax<<<BB * KK, 256, 0, stream>>>(sim, kxyz_t, out_vcp);
}

// Round 15
// 71.200 us; speedup vs baseline: 3.3296x; 2.3508x over previous
//
#include <hip/hip_runtime.h>
#include <math.h>

#define BB 2
#define NPTS 1024
#define KK 64
#define NSZ 32
#define CC 1331      // 11^3
#define FF 32
#define RAD2 1.0f
#define NCOL 121     // 11*11 (ix,iy) columns
#define NRNG 4       // point ranges per batch (256 pts each)

// ---------------- K1: feature MLPs + score + tgt (x,y,z,|t|^2) + A-precompute ------
__global__ __launch_bounds__(64)
void k_features(const float* __restrict__ src_pts, const float* __restrict__ tgt_pts,
                const float* __restrict__ W1, const float* __restrict__ b1,
                const float* __restrict__ W2, const float* __restrict__ b2,
                const float* __restrict__ Ww1, const float* __restrict__ bw1,
                const float* __restrict__ Ww2, const float* __restrict__ bw2,
                const float* __restrict__ Wd1, const float* __restrict__ bd1,
                float* __restrict__ src_feat, float* __restrict__ tgt_A,
                float* __restrict__ tgt_m2, float* __restrict__ score)
{
    int gid = blockIdx.x * blockDim.x + threadIdx.x;   // 0..4095
    int isTgt = gid >= BB * NPTS;
    int pn = gid & (BB * NPTS - 1);
    int b = pn >> 10, n = pn & 1023;
    const float* pts = isTgt ? tgt_pts : src_pts;
    float p[6];
#pragma unroll
    for (int i = 0; i < 6; i++) p[i] = pts[(b * 6 + i) * NPTS + n];
    float h[FF];
#pragma unroll
    for (int j = 0; j < FF; j++) {
        float a = b1[j];
#pragma unroll
        for (int i = 0; i < 6; i++) a = fmaf(p[i], W1[i * FF + j], a);
        h[j] = fmaxf(a, 0.0f);
    }
    float ft[FF];
#pragma unroll
    for (int j = 0; j < FF; j++) {
        float a = b2[j];
#pragma unroll
        for (int i = 0; i < FF; i++) a = fmaf(h[i], W2[i * FF + j], a);
        ft[j] = fmaxf(a, 0.0f);
    }
    if (isTgt) {
        float x = p[0], y = p[1], z = p[2];
        float4 v; v.x = x; v.y = y; v.z = z; v.w = x * x + y * y + z * z;
        ((float4*)tgt_m2)[b * NPTS + n] = v;
        float av[FF];
#pragma unroll
        for (int j = 0; j < FF; j++) av[j] = bd1[j];
#pragma unroll
        for (int i = 0; i < FF; i++) {
            float fi = ft[i];
#pragma unroll
            for (int j = 0; j < FF; j++)
                av[j] = fmaf(fi, Wd1[(3 + i) * FF + j], av[j]);
        }
#pragma unroll
        for (int j = 0; j < FF; j++) tgt_A[(b * NPTS + n) * FF + j] = av[j];
    } else {
#pragma unroll
        for (int j = 0; j < FF; j++) src_feat[(b * NPTS + n) * FF + j] = ft[j];
        float acc = bw2[0];
#pragma unroll
        for (int j = 0; j < 16; j++) {
            float a = bw1[j];
#pragma unroll
            for (int i = 0; i < FF; i++) a = fmaf(ft[i], Ww1[i * 16 + j], a);
            acc = fmaf(fmaxf(a, 0.0f), Ww2[j], acc);
        }
        score[b * NPTS + n] = acc;
    }
}

// ---------------- K2: rank-based top-K (exact lax.top_k order) ----------------
__global__ __launch_bounds__(256)
void k_rank(const float* __restrict__ score, const float* __restrict__ src_pts,
            const float* __restrict__ R,
            int* __restrict__ key_idx, float* __restrict__ kxyz,
            float* __restrict__ kxyz_t, float* __restrict__ out_kxyz)
{
    int blk = blockIdx.x;            // 0..BB*16-1
    int b = blk >> 4;
    int pbase = (blk & 15) << 6;     // 64 points per block
    int t = threadIdx.x;
    int sub = t & 3;                 // j-partition 0..3
    int lp = t >> 2;                 // local point 0..63
    int n = pbase + lp;
    __shared__ float sc[NPTS];
    for (int i = t; i < NPTS; i += 256) sc[i] = score[b * NPTS + i];
    __syncthreads();
    float s = sc[n];
    int rank = 0;
#pragma unroll 8
    for (int jj = 0; jj < 256; jj++) {
        int j = (jj << 2) | sub;
        float sj = sc[j];
        bool before = (sj > s) || (sj == s && j < n);
        rank += before ? 1 : 0;
    }
    rank += __shfl_xor(rank, 1, 64);
    rank += __shfl_xor(rank, 2, 64);
    if (sub == 0 && rank < KK) {
        key_idx[b * KK + rank] = n;
        float x = src_pts[(b * 6 + 0) * NPTS + n];
        float y = src_pts[(b * 6 + 1) * NPTS + n];
        float z = src_pts[(b * 6 + 2) * NPTS + n];
        int o = (b * KK + rank) * 3;
        kxyz[o] = x; kxyz[o + 1] = y; kxyz[o + 2] = z;
        out_kxyz[o] = x; out_kxyz[o + 1] = y; out_kxyz[o + 2] = z;
#pragma unroll
        for (int i = 0; i < 3; i++)
            kxyz_t[o + i] = R[i * 3 + 0] * x + R[i * 3 + 1] * y + R[i * 3 + 2] * z;
    }
}

// ---------------- K3: separable NN scan, NRNG=4 (256-pt ranges) ----------------
// grid = 128 bk x 4 ranges. Block = 256 thr = 2 units x 128 (121 active);
// unit u scans 128 points. part[(bk*4+r)*CC + c] = (best d', global point idx);
// merge order (r asc, u asc, i asc) == point order -> exact argmin semantics.
__global__ __launch_bounds__(256)
void k_scan(const float* __restrict__ kxyz_t, const float* __restrict__ tgt_m2,
            float2* __restrict__ part)
{
    int bid = blockIdx.x;
    int bk = bid >> 2, r = bid & 3;
    int b = bk >> 6;
    int t = threadIdx.x;
    int u = t >> 7, lt = t & 127;
    __shared__ float4 P[256];            // 4 KB
    __shared__ float2 pbuf[2][NCOL][11]; // 21.3 KB
    P[t] = ((const float4*)tgt_m2)[(b << 10) + (r << 8) + t];
    float kx = kxyz_t[bk * 3 + 0], ky = kxyz_t[bk * 3 + 1], kz = kxyz_t[bk * 3 + 2];
    float kx2 = -2.0f * kx, ky2 = -2.0f * ky, kz2 = -2.0f * kz;
    bool active = lt < NCOL;
    int pc = active ? lt : 0;
    int ixv = pc / 11, iyv = pc - ixv * 11;
    float gx2 = -2.0f * (-2.0f + ixv * 0.4f);
    float gy2 = -2.0f * (-2.0f + iyv * 0.4f);
    float gz2[11];
#pragma unroll
    for (int iz = 0; iz < 11; iz++) gz2[iz] = -2.0f * (-2.0f + iz * 0.4f);
    float best[11]; int bn[11];
#pragma unroll
    for (int iz = 0; iz < 11; iz++) { best[iz] = 3.0e38f; bn[iz] = 0; }
    __syncthreads();
    if (active) {
        const int pb = u << 7;           // unit scans 128 points
#pragma unroll 8
        for (int i = 0; i < 128; i++) {
            float4 v = P[pb + i];        // wave-uniform addr -> LDS broadcast
            float a = fmaf(kx2, v.x, fmaf(ky2, v.y, fmaf(kz2, v.z, v.w)));
            float e = fmaf(gx2, v.x, fmaf(gy2, v.y, a));
#pragma unroll
            for (int iz = 0; iz < 11; iz++) {
                float d = fmaf(gz2[iz], v.z, e);
                bool l = d < best[iz];   // strict <: first-min in scan order
                best[iz] = l ? d : best[iz];
                bn[iz] = l ? i : bn[iz];
            }
        }
#pragma unroll
        for (int iz = 0; iz < 11; iz++)
            pbuf[u][lt][iz] = make_float2(best[iz], __int_as_float(bn[iz] + (u << 7)));
    }
    __syncthreads();
    if (u == 0 && active) {
        int cbase = ((bk << 2) + r) * CC + lt * 11;  // c = p*11 + iz (contiguous)
#pragma unroll
        for (int iz = 0; iz < 11; iz++) {
            float2 r0 = pbuf[0][lt][iz], r1 = pbuf[1][lt][iz];
            float2 m = (r1.x < r0.x) ? r1 : r0;      // tie -> unit 0 = lower points
            part[cbase + iz] = make_float2(m.x,
                __int_as_float(__float_as_int(m.y) + (r << 8)));
        }
    }
}

// ---------------- K4: fused {radius-group + src dfe + maxpool} + merge + mlp -------
// 768 blocks x 256 thr. Each block first recomputes its bk's src_emb in LDS
// (verbatim gemb math, 6x redundant across chunks), then thread-per-candidate:
// merge 4 partials -> gather A -> slim dfe -> sim.
__global__ __launch_bounds__(256)
void k_mlp(const float2* __restrict__ part, const float* __restrict__ kxyz_t,
           const float* __restrict__ kxyz, const int* __restrict__ key_idx,
           const float* __restrict__ src_feat,
           const float* __restrict__ tgt_m2, const float* __restrict__ tgt_A,
           const float* __restrict__ Wd1, const float* __restrict__ bd1,
           const float* __restrict__ Wd2, const float* __restrict__ bd2,
           float* __restrict__ sim)
{
    const int NCH = 6;                   // ceil(1331/256)
    int bid = blockIdx.x;
    int chunk = bid % NCH;
    int bk = bid / NCH;
    int b = bk >> 6, kk = bk & 63;
    int t = threadIdx.x;
    __shared__ float kxs[KK][3];
    __shared__ int gidx[NSZ];
    __shared__ float hb[NSZ][FF + 1];    // +1 pad: avoid bank alias on layer-2 reads
    __shared__ float eb[NSZ][FF + 1];
    __shared__ float semb[FF];
    if (t < KK) {
        kxs[t][0] = kxyz[(b * KK + t) * 3 + 0];
        kxs[t][1] = kxyz[(b * KK + t) * 3 + 1];
        kxs[t][2] = kxyz[(b * KK + t) * 3 + 2];
    }
    __syncthreads();
    if (t < KK) {                        // wave 0: ballot grouping (verbatim gemb)
        float cx = kxs[kk][0], cy = kxs[kk][1], cz = kxs[kk][2];
        float dx = kxs[t][0] - cx, dy = kxs[t][1] - cy, dz = kxs[t][2] - cz;
        float sq = dx * dx + dy * dy + dz * dz;
        unsigned long long mask = __ballot(sq <= RAD2);
        if (t < NSZ) {
            int cnt = __popcll(mask);
            int want = (t < cnt) ? t : 0;
            unsigned long long mm = mask;
            for (int q = 0; q < want; q++) mm &= (mm - 1);
            gidx[t] = __ffsll(mm) - 1;
        }
    }
    __syncthreads();
    {   // layer 1: 256 thr = 32 neighbors x 8 j-groups of 4
        int s = t >> 3, jb = (t & 7) << 2;
        int g = gidx[s];
        float cx = kxs[kk][0], cy = kxs[kk][1], cz = kxs[kk][2];
        float xr = kxs[g][0] - cx, yr = kxs[g][1] - cy, zr = kxs[g][2] - cz;
        int orig = key_idx[b * KK + g];
        const float* fz = &src_feat[(b * NPTS + orig) * FF];
        float fr[FF];
#pragma unroll
        for (int i = 0; i < FF; i++) fr[i] = fz[i];
#pragma unroll
        for (int jj = 0; jj < 4; jj++) {
            int j = jb + jj;
            float a = bd1[j];
            a = fmaf(xr, Wd1[0 * FF + j], a);
            a = fmaf(yr, Wd1[1 * FF + j], a);
            a = fmaf(zr, Wd1[2 * FF + j], a);
#pragma unroll
            for (int i = 0; i < FF; i++) a = fmaf(fr[i], Wd1[(3 + i) * FF + j], a);
            hb[s][j] = fmaxf(a, 0.0f);
        }
    }
    __syncthreads();
    {   // layer 2
        int s = t >> 3, jb = (t & 7) << 2;
#pragma unroll
        for (int jj = 0; jj < 4; jj++) {
            int j = jb + jj;
            float a = bd2[j];
#pragma unroll
            for (int i = 0; i < FF; i++) a = fmaf(hb[s][i], Wd2[i * FF + j], a);
            eb[s][j] = fmaxf(a, 0.0f);
        }
    }
    __syncthreads();
    if (t < FF) {                        // maxpool, ascending s (matches gemb)
        float m = eb[0][t];
#pragma unroll
        for (int s2 = 1; s2 < NSZ; s2++) m = fmaxf(m, eb[s2][t]);
        semb[t] = m;
    }
    __syncthreads();
    // ---------------- candidate phase (round-12 verbatim, semb from LDS) ----------
    int c = chunk * 256 + t;
    int cc = min(c, CC - 1);
    float2 rb = part[(bk << 2) * CC + cc];
#pragma unroll
    for (int r = 1; r < NRNG; r++) {
        float2 o = part[((bk << 2) + r) * CC + cc];
        if (o.x < rb.x) rb = o;          // ascending r, strict <
    }
    int nb = __float_as_int(rb.y);
    float4 nv = ((const float4*)tgt_m2)[(b << 10) + nb];
    const float4* az = (const float4*)&tgt_A[((b << 10) + nb) * FF];
    float h[FF];
#pragma unroll
    for (int i = 0; i < FF / 4; i++) {
        float4 v = az[i];
        h[i * 4 + 0] = v.x; h[i * 4 + 1] = v.y; h[i * 4 + 2] = v.z; h[i * 4 + 3] = v.w;
    }
    int ixv = cc / 121, rem = cc - ixv * 121, iyv = rem / 11, izv = rem - iyv * 11;
    float cx = kxyz_t[bk * 3 + 0] + (-2.0f + ixv * 0.4f);
    float cy = kxyz_t[bk * 3 + 1] + (-2.0f + iyv * 0.4f);
    float cz = kxyz_t[bk * 3 + 2] + (-2.0f + izv * 0.4f);
    float x0 = cx - nv.x, x1 = cy - nv.y, x2 = cz - nv.z;
#pragma unroll
    for (int j = 0; j < FF; j++) {
        float a = h[j];
        a = fmaf(x0, Wd1[0 * FF + j], a);
        a = fmaf(x1, Wd1[1 * FF + j], a);
        a = fmaf(x2, Wd1[2 * FF + j], a);
        h[j] = fmaxf(a, 0.0f);
    }
    float sv = 0.0f;
#pragma unroll
    for (int j = 0; j < FF; j++) {
        float a = bd2[j];
#pragma unroll
        for (int i = 0; i < FF; i++) a = fmaf(h[i], Wd2[i * FF + j], a);
        sv = fmaf(fmaxf(a, 0.0f), semb[j], sv);
    }
    if (c < CC) sim[bk * CC + c] = sv;
}

// ---------------- K5: softmax over candidates + weighted sum ----------------
__global__ __launch_bounds__(256)
void k_softmax(const float* __restrict__ sim, const float* __restrict__ kxyz_t,
               float* __restrict__ out_vcp)
{
    int bk = blockIdx.x;
    int t = threadIdx.x;
    __shared__ float red[256];
    __shared__ float4 red4[256];
    float kx = kxyz_t[bk * 3 + 0], ky = kxyz_t[bk * 3 + 1], kz = kxyz_t[bk * 3 + 2];
    float lm = -3.0e38f;
    for (int c = t; c < CC; c += 256) lm = fmaxf(lm, sim[bk * CC + c]);
    red[t] = lm;
    __syncthreads();
    for (int s2 = 128; s2 > 0; s2 >>= 1) {
        if (t < s2) red[t] = fmaxf(red[t], red[t + s2]);
        __syncthreads();
    }
    float m = red[0];
    float se = 0.f, sx = 0.f, sy = 0.f, sz = 0.f;
    for (int c = t; c < CC; c += 256) {
        float e = expf(sim[bk * CC + c] - m);
        int ix = c / 121, rem = c - ix * 121, iy = rem / 11, iz = rem - iy * 11;
        float cxx = kx + (-2.0f + ix * 0.4f);
        float cyy = ky + (-2.0f + iy * 0.4f);
        float czz = kz + (-2.0f + iz * 0.4f);
        se += e;
        sx = fmaf(e, cxx, sx);
        sy = fmaf(e, cyy, sy);
        sz = fmaf(e, czz, sz);
    }
    red4[t] = make_float4(se, sx, sy, sz);
    __syncthreads();
    for (int s2 = 128; s2 > 0; s2 >>= 1) {
        if (t < s2) {
            float4 a = red4[t], bq = red4[t + s2];
            red4[t] = make_float4(a.x + bq.x, a.y + bq.y, a.z + bq.z, a.w + bq.w);
        }
        __syncthreads();
    }
    if (t == 0) {
        float4 r = red4[0];
        out_vcp[bk * 3 + 0] = r.y / r.x;
        out_vcp[bk * 3 + 1] = r.z / r.x;
        out_vcp[bk * 3 + 2] = r.w / r.x;
    }
}

extern "C" void kernel_launch(void* const* d_in, const int* in_sizes, int n_in,
                              void* d_out, int out_size, void* d_ws, size_t ws_size,
                              hipStream_t stream)
{
    (void)in_sizes; (void)n_in; (void)out_size; (void)ws_size;
    const float* src_pts = (const float*)d_in[0];
    const float* tgt_pts = (const float*)d_in[1];
    const float* R_init  = (const float*)d_in[2];
    const float* W1  = (const float*)d_in[4];
    const float* b1  = (const float*)d_in[5];
    const float* W2  = (const float*)d_in[6];
    const float* b2  = (const float*)d_in[7];
    const float* Ww1 = (const float*)d_in[8];
    const float* bw1 = (const float*)d_in[9];
    const float* Ww2 = (const float*)d_in[10];
    const float* bw2 = (const float*)d_in[11];
    const float* Wd1 = (const float*)d_in[12];
    const float* bd1 = (const float*)d_in[13];
    const float* Wd2 = (const float*)d_in[14];
    const float* bd2 = (const float*)d_in[15];

    float* ws = (float*)d_ws;
    float* src_feat = ws;                              // 65536
    float* tgt_A    = src_feat + BB * NPTS * FF;       // 65536
    float* tgt_m2   = tgt_A + BB * NPTS * FF;          // 8192
    float* score    = tgt_m2 + BB * NPTS * 4;          // 2048
    int*   key_idx  = (int*)(score + BB * NPTS);       // 128
    float* kxyz     = (float*)(key_idx + BB * KK);     // 384
    float* kxyz_t   = kxyz + BB * KK * 3;              // 384
    float* sim      = kxyz_t + BB * KK * 3;            // 170368
    float2* part    = (float2*)(sim + BB * KK * CC);   // 128*4*1331 float2 = 5.45 MB

    float* out_kxyz = (float*)d_out;
    float* out_vcp  = out_kxyz + BB * KK * 3;

    k_features<<<64, 64, 0, stream>>>(
        src_pts, tgt_pts, W1, b1, W2, b2, Ww1, bw1, Ww2, bw2, Wd1, bd1,
        src_feat, tgt_A, tgt_m2, score);
    k_rank<<<BB * 16, 256, 0, stream>>>(score, src_pts, R_init,
                                        key_idx, kxyz, kxyz_t, out_kxyz);
    k_scan<<<BB * KK * NRNG, 256, 0, stream>>>(kxyz_t, tgt_m2, part);
    k_mlp<<<BB * KK * 6, 256, 0, stream>>>(part, kxyz_t, kxyz, key_idx, src_feat,
                                           tgt_m2, tgt_A, Wd1, bd1, Wd2, bd2, sim);
    k_softmax<<<BB * KK, 256, 0, stream>>>(sim, kxyz_t, out_vcp);
}